// Round 2
// baseline (1039.909 us; speedup 1.0000x reference)
//
#include <hip/hip_runtime.h>

// StableHyperNet on MI355X (gfx950)
// H=5 T=15 N_INT=15 N_LEAF=16 D=512 ENC=64 GEN=128 TOTAL=139440
// N_SUP=4096 N_QRY=32768 C=100

#define TOTAL 139440
#define I0 115200      // T*N_INT*D
#define I1 115425      // + T*N_INT
#define I2 139425      // + T*N_LEAF*C
#define NPAIR 38       // ceil(75 trees / 2)

typedef _Float16 f16;
typedef _Float16 f16x8 __attribute__((ext_vector_type(8)));
typedef _Float16 f16x4 __attribute__((ext_vector_type(4)));
typedef float f32x16 __attribute__((ext_vector_type(16)));

// ---------------------------------------------------------------------------
// K1: support encoder. grid (64, 5) x 256. Each wave handles 16 support rows,
// lane = enc channel e (ENC==64==wavefront). Produces ctx_sum[h][e] via atomics.
__global__ __launch_bounds__(256) void k1_encode(
    const float* __restrict__ Xs, const float* __restrict__ w1,
    const float* __restrict__ b1, const float* __restrict__ lng,
    const float* __restrict__ lnb, const float* __restrict__ w2,
    float* __restrict__ ctx_sum)
{
  const int h = blockIdx.y;
  const int tid = threadIdx.x;
  const int lane = tid & 63;
  const int wave = tid >> 6;
  const int s0 = blockIdx.x * 64 + wave * 16;
  __shared__ float lsg[4][64];

  // enc_w2 column resident in registers: w2r[e] = w2[h][e][lane]
  float w2r[64];
  #pragma unroll
  for (int e = 0; e < 64; ++e) w2r[e] = w2[(h * 64 + e) * 64 + lane];

  float acc[16];
  #pragma unroll
  for (int r = 0; r < 16; ++r) acc[r] = 0.f;

  const float* wp = w1 + h * 512 * 64;
  for (int d4 = 0; d4 < 128; ++d4) {
    const int d = d4 * 4;
    const float wa = wp[(d + 0) * 64 + lane];
    const float wb = wp[(d + 1) * 64 + lane];
    const float wc = wp[(d + 2) * 64 + lane];
    const float wd = wp[(d + 3) * 64 + lane];
    #pragma unroll
    for (int r = 0; r < 16; ++r) {
      const float4 x4 = *(const float4*)(Xs + (s0 + r) * 512 + d);
      acc[r] = fmaf(x4.x, wa, acc[r]);
      acc[r] = fmaf(x4.y, wb, acc[r]);
      acc[r] = fmaf(x4.z, wc, acc[r]);
      acc[r] = fmaf(x4.w, wd, acc[r]);
    }
  }

  const float bb = b1[h * 64 + lane];
  const float ge = lng[h * 64 + lane];
  const float be = lnb[h * 64 + lane];
  float ctxacc = 0.f;

  for (int r = 0; r < 16; ++r) {
    const float v = acc[r] + bb;
    float s = v, s2 = v * v;
    #pragma unroll
    for (int m = 1; m < 64; m <<= 1) {
      s  += __shfl_xor(s, m, 64);
      s2 += __shfl_xor(s2, m, 64);
    }
    const float mu = s * (1.f / 64.f);
    const float var = fmaxf(s2 * (1.f / 64.f) - mu * mu, 0.f);
    const float y = (v - mu) * rsqrtf(var + 1e-5f) * ge + be;
    const float gl = 0.5f * y * (1.f + erff(y * 0.70710678118654752f)); // exact gelu
    lsg[wave][lane] = gl;          // wave-private row; in-order LDS within wave
    float sm = 0.f;
    #pragma unroll
    for (int e4 = 0; e4 < 16; ++e4) {
      const float4 g4 = *(const float4*)(&lsg[wave][e4 * 4]);
      sm = fmaf(g4.x, w2r[e4 * 4 + 0], sm);
      sm = fmaf(g4.y, w2r[e4 * 4 + 1], sm);
      sm = fmaf(g4.z, w2r[e4 * 4 + 2], sm);
      sm = fmaf(g4.w, w2r[e4 * 4 + 3], sm);
    }
    ctxacc += sm;
  }
  atomicAdd(&ctx_sum[h * 64 + lane], ctxacc);
}

// ---------------------------------------------------------------------------
// K2: ctx mean + enc_b2, g = gelu(ctx@gen_w1 + gen_b1), hw softmax, inv-temp.
__global__ __launch_bounds__(256) void k2_ctx(
    const float* __restrict__ eb2, const float* __restrict__ gw1,
    const float* __restrict__ gb1, const float* __restrict__ hwin,
    const float* __restrict__ tempin, const float* __restrict__ ctx_sum,
    float* __restrict__ g_out, float* __restrict__ hwit)
{
  __shared__ float ctx[320];
  const int tid = threadIdx.x;
  for (int i = tid; i < 320; i += 256)
    ctx[i] = ctx_sum[i] * (1.f / 4096.f) + eb2[i];
  __syncthreads();
  for (int i = tid; i < 640; i += 256) {
    const int h = i >> 7, j = i & 127;
    float a = gb1[i];
    for (int e = 0; e < 64; ++e)
      a = fmaf(ctx[h * 64 + e], gw1[(h * 64 + e) * 128 + j], a);
    g_out[i] = 0.5f * a * (1.f + erff(a * 0.70710678118654752f));
  }
  if (tid == 0) {
    float m = hwin[0];
    for (int i = 1; i < 5; ++i) m = fmaxf(m, hwin[i]);
    float ex[5]; float se = 0.f;
    for (int i = 0; i < 5; ++i) { ex[i] = __expf(hwin[i] - m); se += ex[i]; }
    for (int i = 0; i < 5; ++i) hwit[i] = ex[i] / se;
    float tp = tempin[0];
    tp = fminf(fmaxf(tp, 0.1f), 2.0f);
    hwit[5] = 1.0f / tp;
  }
}

// ---------------------------------------------------------------------------
// K3: params = 2*tanh(g @ gen_w2 + gen_b2). Streams 357 MB — HBM-bound.
// grid (137, 5) x 256, one float4 of outputs per thread.
__global__ __launch_bounds__(256) void k3_params(
    const float* __restrict__ gv, const float* __restrict__ gw2,
    const float* __restrict__ gb2, float* __restrict__ params)
{
  const int h = blockIdx.y;
  __shared__ float gl[128];
  const int tid = threadIdx.x;
  if (tid < 128) gl[tid] = gv[h * 128 + tid];
  __syncthreads();
  const long i4 = (long)blockIdx.x * 256 + tid;
  if (i4 >= TOTAL / 4) return;
  const long i = i4 * 4;
  const float* wp = gw2 + (long)h * 128 * TOTAL + i;
  float4 a = *(const float4*)(gb2 + (long)h * TOTAL + i);
  #pragma unroll 4
  for (int k = 0; k < 128; ++k) {
    const float4 w4 = *(const float4*)(wp + (long)k * TOTAL);
    const float gk = gl[k];
    a.x = fmaf(gk, w4.x, a.x);
    a.y = fmaf(gk, w4.y, a.y);
    a.z = fmaf(gk, w4.z, a.z);
    a.w = fmaf(gk, w4.w, a.w);
  }
  float4 o;
  o.x = 2.f * tanhf(a.x);
  o.y = 2.f * tanhf(a.y);
  o.z = 2.f * tanhf(a.z);
  o.w = 2.f * tanhf(a.w);
  *(float4*)(params + (long)h * TOTAL + i) = o;
}

// ---------------------------------------------------------------------------
// K4a: pack split_w into fp16 B-fragment order for mfma_f32_32x32x16_f16.
// wpk[pair][kk 0..31][lane 0..63][j 0..7]:
//   value = split_w[tree = 2*pair + ((lane&31)>>4)][n = lane&15][d = kk*16 + (lane>>5)*8 + j]
// zeros for n==15 (node pad) and tree==75 (pair pad). grid 304 x 256 (exact).
__global__ __launch_bounds__(256) void k4a_packw(
    const float* __restrict__ params, f16* __restrict__ wpk)
{
  const int t0 = blockIdx.x * 256 + threadIdx.x;   // < 38*2048 = 77824
  const int lane = t0 & 63;
  const int kk = (t0 >> 6) & 31;
  const int pair = t0 >> 11;
  const int cl = lane & 31;
  const int tree = pair * 2 + (cl >> 4);
  const int n = cl & 15;
  f16x8 v;
  if (tree < 75 && n < 15) {
    const int h = tree / 15;
    const int t = tree - h * 15;
    const int dbase = kk * 16 + (lane >> 5) * 8;
    const float* src = params + (long)h * TOTAL + ((t * 15 + n) * 512 + dbase);
    const float4 x0 = *(const float4*)(src);
    const float4 x1 = *(const float4*)(src + 4);
    v[0] = (f16)x0.x; v[1] = (f16)x0.y; v[2] = (f16)x0.z; v[3] = (f16)x0.w;
    v[4] = (f16)x1.x; v[5] = (f16)x1.y; v[6] = (f16)x1.z; v[7] = (f16)x1.w;
  } else {
    #pragma unroll
    for (int j = 0; j < 8; ++j) v[j] = (f16)0.f;
  }
  *(f16x8*)(wpk + (long)t0 * 8) = v;
}

// ---------------------------------------------------------------------------
// K4b: W2[g][leaf][c] = softmax_c(leaf_logits*it) * tree_w[g] * hw[h], packed as
// fp16 B-frags (K=16 = one tree's leaves): w2pk[g][ct][lane][j],
// lane = ((leaf>>3)<<5)|(c&31), j = leaf&7, ct = c>>5. grid 1200 x 128.
__global__ __launch_bounds__(128) void k4b_w2(
    const float* __restrict__ params, const float* __restrict__ hwit,
    f16* __restrict__ w2pk)
{
  const int g = blockIdx.x >> 4;
  const int leaf = blockIdx.x & 15;
  const int h = g / 15, t = g - h * 15;
  const float it = hwit[5];
  float m = -1e30f;
  float tl[15];
  #pragma unroll
  for (int i = 0; i < 15; ++i) {
    tl[i] = params[(long)h * TOTAL + I2 + i];
    m = fmaxf(m, tl[i]);
  }
  float se = 0.f;
  #pragma unroll
  for (int i = 0; i < 15; ++i) se += __expf(tl[i] - m);
  const float tw = __expf(tl[t] - m) / se;
  const float scale = tw * hwit[h];

  const int c = threadIdx.x;
  __shared__ float red[128];
  float lg = -1e30f;
  if (c < 100) lg = params[(long)h * TOTAL + I1 + ((t * 16 + leaf) * 100 + c)] * it;
  red[c] = lg;
  __syncthreads();
  for (int s = 64; s > 0; s >>= 1) {
    if (c < s) red[c] = fmaxf(red[c], red[c + s]);
    __syncthreads();
  }
  const float mx = red[0];
  __syncthreads();
  const float exv = (c < 100) ? __expf(lg - mx) : 0.f;
  red[c] = exv;
  __syncthreads();
  for (int s = 64; s > 0; s >>= 1) {
    if (c < s) red[c] += red[c + s];
    __syncthreads();
  }
  const float inv = 1.f / red[0];
  if (c < 100) {
    const float val = exv * inv * scale;
    const int ln = ((leaf >> 3) << 5) | (c & 31);
    const int j = leaf & 7;
    const int ct = c >> 5;
    w2pk[(((long)g * 4 + ct) * 64 + ln) * 8 + j] = (f16)val;
  }
}

// ---------------------------------------------------------------------------
// K5: fused query kernel. grid 1024 x 256. Block = 32 queries (staged once into
// LDS in A-frag order), 4 waves split the 38 tree-pairs (2 pairs per group ->
// 4 independent MFMA accumulation chains). dec -> LDS transpose -> reach ->
// fp16 A-frag -> out MFMA. Cross-wave out reduction via LDS at the end.
__global__ __launch_bounds__(256, 2) void k5_query(
    const float* __restrict__ Xq, const float* __restrict__ params,
    const f16* __restrict__ wpk, const f16* __restrict__ w2pk,
    const float* __restrict__ hwit, float* __restrict__ out)
{
  __shared__ __align__(16) f16 xf[32 * 64 * 8];   // 32 KB: [kk][lane][j]
  __shared__ float decs[4][32][34];               // 17 KB: per-wave dec tile (pad 34)
  __shared__ float ored[4][1024];                 // 16 KB: out reduction staging

  const int tid = threadIdx.x;
  const int lane = tid & 63;
  const int wave = tid >> 6;
  const int qbase = blockIdx.x * 32;
  const float it = hwit[5];
  const int col = lane & 31;
  const int khalf = lane >> 5;

  // ---- stage X (fp32 -> fp16) into exact A-fragment layout
  {
    const int q = tid >> 3;
    const int db = (tid & 7) * 4;
    const float* xr = Xq + (long)(qbase + q) * 512;
    #pragma unroll
    for (int i = 0; i < 16; ++i) {
      const int d = db + i * 32;
      const float4 x4 = *(const float4*)(xr + d);
      const int kk = d >> 4;
      const int ln = q + 32 * ((d & 15) >> 3);
      const int j0 = d & 7;
      f16x4 v;
      v[0] = (f16)x4.x; v[1] = (f16)x4.y; v[2] = (f16)x4.z; v[3] = (f16)x4.w;
      *(f16x4*)(&xf[(kk * 64 + ln) * 8 + j0]) = v;
    }
  }
  __syncthreads();

  f32x16 oacc[4];
  #pragma unroll
  for (int ct = 0; ct < 4; ++ct)
    #pragma unroll
    for (int r = 0; r < 16; ++r) oacc[ct][r] = 0.f;

  auto process = [&](const f32x16& S0, const f32x16& S1, int pp) {
    // bias + sigmoid, write dec tile (D layout: col = lane&31, row = (r&3)+8*(r>>2)+4*(lane>>5))
    const int tree = pp * 2 + (col >> 4);
    const int treec = (tree < 75) ? tree : 74;   // pad column: junk, never read
    const int hh2 = treec / 15;
    const int tt2 = treec - hh2 * 15;
    const float bn = params[(long)hh2 * TOTAL + I0 + tt2 * 15 + (col & 15)];
    #pragma unroll
    for (int r = 0; r < 16; ++r) {
      const float z = (S0[r] + S1[r] + bn) * it;
      const float dv = 1.f / (1.f + __expf(-z));
      const int row = (r & 3) + 8 * (r >> 2) + 4 * khalf;
      decs[wave][row][col] = dv;
    }
    // reach + out-MFMA per tree of the pair. lane: q = col, leaves khalf*8..+7
    #pragma unroll
    for (int tf = 0; tf < 2; ++tf) {
      const int g = pp * 2 + tf;
      if (g < 75) {
        const int cb = tf * 16;
        const float* dsr = &decs[wave][col][cb];
        const float d0v = dsr[0];
        const float f0 = khalf ? d0v : 1.f - d0v;
        const float d1v = dsr[1 + khalf];
        const float p10 = f0 * (1.f - d1v);
        const float p11 = f0 * d1v;
        const float d2a = dsr[3 + 2 * khalf];
        const float d2b = dsr[4 + 2 * khalf];
        float p2[4];
        p2[0] = p10 * (1.f - d2a);
        p2[1] = p10 * d2a;
        p2[2] = p11 * (1.f - d2b);
        p2[3] = p11 * d2b;
        float d3[4];
        #pragma unroll
        for (int u = 0; u < 4; ++u) d3[u] = dsr[7 + 4 * khalf + u];
        f16x8 rf;
        #pragma unroll
        for (int mm = 0; mm < 8; ++mm) {
          const float rv = p2[mm >> 1] * ((mm & 1) ? d3[mm >> 1] : (1.f - d3[mm >> 1]));
          rf[mm] = (f16)rv;
        }
        const f16x8* w2p = (const f16x8*)w2pk + ((long)g * 4) * 64 + lane;
        oacc[0] = __builtin_amdgcn_mfma_f32_32x32x16_f16(rf, w2p[0],   oacc[0], 0, 0, 0);
        oacc[1] = __builtin_amdgcn_mfma_f32_32x32x16_f16(rf, w2p[64],  oacc[1], 0, 0, 0);
        oacc[2] = __builtin_amdgcn_mfma_f32_32x32x16_f16(rf, w2p[128], oacc[2], 0, 0, 0);
        oacc[3] = __builtin_amdgcn_mfma_f32_32x32x16_f16(rf, w2p[192], oacc[3], 0, 0, 0);
      }
    }
  };

  // main loop: wave handles pairs {p, p+4} per group, p = wave, wave+8, ...
  for (int p = wave; p < NPAIR; p += 8) {
    const bool has2 = (p + 4 < NPAIR);
    const f16x8* wha = (const f16x8*)wpk + (long)p * 32 * 64 + lane;
    const f16x8* whb = has2 ? ((const f16x8*)wpk + (long)(p + 4) * 32 * 64 + lane) : wha;
    f32x16 Sa0, Sa1, Sb0, Sb1;
    #pragma unroll
    for (int r = 0; r < 16; ++r) { Sa0[r] = 0.f; Sa1[r] = 0.f; Sb0[r] = 0.f; Sb1[r] = 0.f; }
    #pragma unroll
    for (int kk = 0; kk < 32; kk += 2) {
      const f16x8 af0 = *(const f16x8*)(&xf[(kk * 64 + lane) * 8]);
      const f16x8 af1 = *(const f16x8*)(&xf[((kk + 1) * 64 + lane) * 8]);
      const f16x8 wa0 = wha[(long)kk * 64];
      const f16x8 wa1 = wha[(long)(kk + 1) * 64];
      const f16x8 wb0 = whb[(long)kk * 64];
      const f16x8 wb1 = whb[(long)(kk + 1) * 64];
      Sa0 = __builtin_amdgcn_mfma_f32_32x32x16_f16(af0, wa0, Sa0, 0, 0, 0);
      Sb0 = __builtin_amdgcn_mfma_f32_32x32x16_f16(af0, wb0, Sb0, 0, 0, 0);
      Sa1 = __builtin_amdgcn_mfma_f32_32x32x16_f16(af1, wa1, Sa1, 0, 0, 0);
      Sb1 = __builtin_amdgcn_mfma_f32_32x32x16_f16(af1, wb1, Sb1, 0, 0, 0);
    }
    process(Sa0, Sa1, p);
    if (has2) process(Sb0, Sb1, p + 4);
  }

  // ---- cross-wave reduction of out accumulators + store
  __syncthreads();
  #pragma unroll
  for (int ct = 0; ct < 4; ++ct) {
    #pragma unroll
    for (int r = 0; r < 16; ++r) {
      const int row = (r & 3) + 8 * (r >> 2) + 4 * khalf;
      ored[wave][row * 32 + col] = oacc[ct][r];
    }
    __syncthreads();
    for (int e = tid; e < 1024; e += 256) {
      const float sm = ored[0][e] + ored[1][e] + ored[2][e] + ored[3][e];
      const int q = e >> 5;
      const int c = ct * 32 + (e & 31);
      if (c < 100) out[(long)(qbase + q) * 100 + c] = sm;
    }
    __syncthreads();
  }
}

// ---------------------------------------------------------------------------
extern "C" void kernel_launch(void* const* d_in, const int* in_sizes, int n_in,
                              void* d_out, int out_size, void* d_ws, size_t ws_size,
                              hipStream_t stream) {
  (void)in_sizes; (void)n_in; (void)out_size; (void)ws_size;
  const float* Xs  = (const float*)d_in[0];
  const float* Xq  = (const float*)d_in[1];
  const float* ew1 = (const float*)d_in[2];
  const float* eb1 = (const float*)d_in[3];
  const float* lng = (const float*)d_in[4];
  const float* lnb = (const float*)d_in[5];
  const float* ew2 = (const float*)d_in[6];
  const float* eb2 = (const float*)d_in[7];
  const float* gw1 = (const float*)d_in[8];
  const float* gb1 = (const float*)d_in[9];
  const float* gw2 = (const float*)d_in[10];
  const float* gb2 = (const float*)d_in[11];
  const float* hwi = (const float*)d_in[12];
  const float* tmp = (const float*)d_in[13];
  float* out = (float*)d_out;

  // ws layout (bytes), all 64B-aligned; total needed = 4,345,056 B
  char* ws = (char*)d_ws;
  float* params = (float*)(ws);                              // 2,788,800
  f16*   wpk    = (f16*)(ws + 2788800);                      // 1,245,184
  f16*   w2pk   = (f16*)(ws + 2788800 + 1245184);            //   307,200
  float* ctxs   = (float*)(ws + 4341184);                    //     1,280
  float* gbuf   = (float*)(ws + 4342464);                    //     2,560
  float* hwit   = (float*)(ws + 4345024);                    //        32

  hipMemsetAsync(ctxs, 0, 1280, stream);
  hipMemsetAsync(w2pk, 0, 307200, stream);

  k1_encode<<<dim3(64, 5), 256, 0, stream>>>(Xs, ew1, eb1, lng, lnb, ew2, ctxs);
  k2_ctx<<<1, 256, 0, stream>>>(eb2, gw1, gb1, hwi, tmp, ctxs, gbuf, hwit);
  k3_params<<<dim3(137, 5), 256, 0, stream>>>(gbuf, gw2, gb2, params);
  k4a_packw<<<304, 256, 0, stream>>>(params, wpk);
  k4b_w2<<<1200, 128, 0, stream>>>(params, hwit, w2pk);
  k5_query<<<1024, 256, 0, stream>>>(Xq, params, wpk, w2pk, hwit, out);
}

// Round 4
// 998.676 us; speedup vs baseline: 1.0413x; 1.0413x over previous
//
#include <hip/hip_runtime.h>

// StableHyperNet on MI355X (gfx950)
// H=5 T=15 N_INT=15 N_LEAF=16 D=512 ENC=64 GEN=128 TOTAL=139440
// N_SUP=4096 N_QRY=32768 C=100

#define TOTAL 139440
#define I0 115200      // T*N_INT*D
#define I1 115425      // + T*N_INT
#define I2 139425      // + T*N_LEAF*C
#define NPAIR 38       // ceil(75 trees / 2)

typedef _Float16 f16;
typedef _Float16 f16x8 __attribute__((ext_vector_type(8)));
typedef _Float16 f16x4 __attribute__((ext_vector_type(4)));
typedef float f32x16 __attribute__((ext_vector_type(16)));

// async global->LDS, 16B per lane; LDS dest = wave-uniform base (+lane*16 by HW)
__device__ __forceinline__ void stage1k(const f16* gsrc, f16* ldst) {
  __builtin_amdgcn_global_load_lds(
      (const __attribute__((address_space(1))) unsigned int*)gsrc,
      (__attribute__((address_space(3))) unsigned int*)ldst, 16, 0, 0);
}

// ---------------------------------------------------------------------------
// K1: support encoder. grid (128, 5) x 256. Each wave handles 8 support rows,
// lane = enc channel e. Produces ctx_sum[h][e] via atomics.
__global__ __launch_bounds__(256) void k1_encode(
    const float* __restrict__ Xs, const float* __restrict__ w1,
    const float* __restrict__ b1, const float* __restrict__ lng,
    const float* __restrict__ lnb, const float* __restrict__ w2,
    float* __restrict__ ctx_sum)
{
  const int h = blockIdx.y;
  const int tid = threadIdx.x;
  const int lane = tid & 63;
  const int wave = tid >> 6;
  const int s0 = blockIdx.x * 32 + wave * 8;
  __shared__ float lsg[4][64];

  float w2r[64];
  #pragma unroll
  for (int e = 0; e < 64; ++e) w2r[e] = w2[(h * 64 + e) * 64 + lane];

  float acc[8];
  #pragma unroll
  for (int r = 0; r < 8; ++r) acc[r] = 0.f;

  const float* wp = w1 + h * 512 * 64;
  for (int d4 = 0; d4 < 128; ++d4) {
    const int d = d4 * 4;
    const float wa = wp[(d + 0) * 64 + lane];
    const float wb = wp[(d + 1) * 64 + lane];
    const float wc = wp[(d + 2) * 64 + lane];
    const float wd = wp[(d + 3) * 64 + lane];
    #pragma unroll
    for (int r = 0; r < 8; ++r) {
      const float4 x4 = *(const float4*)(Xs + (s0 + r) * 512 + d);
      acc[r] = fmaf(x4.x, wa, acc[r]);
      acc[r] = fmaf(x4.y, wb, acc[r]);
      acc[r] = fmaf(x4.z, wc, acc[r]);
      acc[r] = fmaf(x4.w, wd, acc[r]);
    }
  }

  const float bb = b1[h * 64 + lane];
  const float ge = lng[h * 64 + lane];
  const float be = lnb[h * 64 + lane];
  float ctxacc = 0.f;

  for (int r = 0; r < 8; ++r) {
    const float v = acc[r] + bb;
    float s = v, s2 = v * v;
    #pragma unroll
    for (int m = 1; m < 64; m <<= 1) {
      s  += __shfl_xor(s, m, 64);
      s2 += __shfl_xor(s2, m, 64);
    }
    const float mu = s * (1.f / 64.f);
    const float var = fmaxf(s2 * (1.f / 64.f) - mu * mu, 0.f);
    const float y = (v - mu) * rsqrtf(var + 1e-5f) * ge + be;
    const float gl = 0.5f * y * (1.f + erff(y * 0.70710678118654752f)); // exact gelu
    lsg[wave][lane] = gl;
    float sm = 0.f;
    #pragma unroll
    for (int e4 = 0; e4 < 16; ++e4) {
      const float4 g4 = *(const float4*)(&lsg[wave][e4 * 4]);
      sm = fmaf(g4.x, w2r[e4 * 4 + 0], sm);
      sm = fmaf(g4.y, w2r[e4 * 4 + 1], sm);
      sm = fmaf(g4.z, w2r[e4 * 4 + 2], sm);
      sm = fmaf(g4.w, w2r[e4 * 4 + 3], sm);
    }
    ctxacc += sm;
  }
  atomicAdd(&ctx_sum[h * 64 + lane], ctxacc);
}

// ---------------------------------------------------------------------------
// K2: ctx mean + enc_b2, g = gelu(ctx@gen_w1 + gen_b1), hw softmax, inv-temp.
__global__ __launch_bounds__(256) void k2_ctx(
    const float* __restrict__ eb2, const float* __restrict__ gw1,
    const float* __restrict__ gb1, const float* __restrict__ hwin,
    const float* __restrict__ tempin, const float* __restrict__ ctx_sum,
    float* __restrict__ g_out, float* __restrict__ hwit)
{
  __shared__ float ctx[320];
  const int tid = threadIdx.x;
  for (int i = tid; i < 320; i += 256)
    ctx[i] = ctx_sum[i] * (1.f / 4096.f) + eb2[i];
  __syncthreads();
  for (int i = tid; i < 640; i += 256) {
    const int h = i >> 7, j = i & 127;
    float a = gb1[i];
    for (int e = 0; e < 64; ++e)
      a = fmaf(ctx[h * 64 + e], gw1[(h * 64 + e) * 128 + j], a);
    g_out[i] = 0.5f * a * (1.f + erff(a * 0.70710678118654752f));
  }
  if (tid == 0) {
    float m = hwin[0];
    for (int i = 1; i < 5; ++i) m = fmaxf(m, hwin[i]);
    float ex[5]; float se = 0.f;
    for (int i = 0; i < 5; ++i) { ex[i] = __expf(hwin[i] - m); se += ex[i]; }
    for (int i = 0; i < 5; ++i) hwit[i] = ex[i] / se;
    float tp = tempin[0];
    tp = fminf(fmaxf(tp, 0.1f), 2.0f);
    hwit[5] = 1.0f / tp;
  }
}

// ---------------------------------------------------------------------------
// K3: params = 2*tanh(g @ gen_w2 + gen_b2). Streams 357 MB — HBM-bound.
__global__ __launch_bounds__(256) void k3_params(
    const float* __restrict__ gv, const float* __restrict__ gw2,
    const float* __restrict__ gb2, float* __restrict__ params)
{
  const int h = blockIdx.y;
  __shared__ float gl[128];
  const int tid = threadIdx.x;
  if (tid < 128) gl[tid] = gv[h * 128 + tid];
  __syncthreads();
  const long i4 = (long)blockIdx.x * 256 + tid;
  if (i4 >= TOTAL / 4) return;
  const long i = i4 * 4;
  const float* wp = gw2 + (long)h * 128 * TOTAL + i;
  float4 a = *(const float4*)(gb2 + (long)h * TOTAL + i);
  #pragma unroll 8
  for (int k = 0; k < 128; ++k) {
    const float4 w4 = *(const float4*)(wp + (long)k * TOTAL);
    const float gk = gl[k];
    a.x = fmaf(gk, w4.x, a.x);
    a.y = fmaf(gk, w4.y, a.y);
    a.z = fmaf(gk, w4.z, a.z);
    a.w = fmaf(gk, w4.w, a.w);
  }
  float4 o;
  o.x = 2.f * tanhf(a.x);
  o.y = 2.f * tanhf(a.y);
  o.z = 2.f * tanhf(a.z);
  o.w = 2.f * tanhf(a.w);
  *(float4*)(params + (long)h * TOTAL + i) = o;
}

// ---------------------------------------------------------------------------
// K4a: pack split_w into fp16 B-fragment order for mfma_f32_32x32x16_f16.
__global__ __launch_bounds__(256) void k4a_packw(
    const float* __restrict__ params, f16* __restrict__ wpk)
{
  const int t0 = blockIdx.x * 256 + threadIdx.x;   // < 38*2048 = 77824
  const int lane = t0 & 63;
  const int kk = (t0 >> 6) & 31;
  const int pair = t0 >> 11;
  const int cl = lane & 31;
  const int tree = pair * 2 + (cl >> 4);
  const int n = cl & 15;
  f16x8 v;
  if (tree < 75 && n < 15) {
    const int h = tree / 15;
    const int t = tree - h * 15;
    const int dbase = kk * 16 + (lane >> 5) * 8;
    const float* src = params + (long)h * TOTAL + ((t * 15 + n) * 512 + dbase);
    const float4 x0 = *(const float4*)(src);
    const float4 x1 = *(const float4*)(src + 4);
    v[0] = (f16)x0.x; v[1] = (f16)x0.y; v[2] = (f16)x0.z; v[3] = (f16)x0.w;
    v[4] = (f16)x1.x; v[5] = (f16)x1.y; v[6] = (f16)x1.z; v[7] = (f16)x1.w;
  } else {
    #pragma unroll
    for (int j = 0; j < 8; ++j) v[j] = (f16)0.f;
  }
  *(f16x8*)(wpk + (long)t0 * 8) = v;
}

// ---------------------------------------------------------------------------
// K4b: W2[g][leaf][c] = softmax_c(leaf_logits*it) * tree_w[g] * hw[h], fp16 B-frags.
__global__ __launch_bounds__(128) void k4b_w2(
    const float* __restrict__ params, const float* __restrict__ hwit,
    f16* __restrict__ w2pk)
{
  const int g = blockIdx.x >> 4;
  const int leaf = blockIdx.x & 15;
  const int h = g / 15, t = g - h * 15;
  const float it = hwit[5];
  float m = -1e30f;
  float tl[15];
  #pragma unroll
  for (int i = 0; i < 15; ++i) {
    tl[i] = params[(long)h * TOTAL + I2 + i];
    m = fmaxf(m, tl[i]);
  }
  float se = 0.f;
  #pragma unroll
  for (int i = 0; i < 15; ++i) se += __expf(tl[i] - m);
  const float tw = __expf(tl[t] - m) / se;
  const float scale = tw * hwit[h];

  const int c = threadIdx.x;
  __shared__ float red[128];
  float lg = -1e30f;
  if (c < 100) lg = params[(long)h * TOTAL + I1 + ((t * 16 + leaf) * 100 + c)] * it;
  red[c] = lg;
  __syncthreads();
  for (int s = 64; s > 0; s >>= 1) {
    if (c < s) red[c] = fmaxf(red[c], red[c + s]);
    __syncthreads();
  }
  const float mx = red[0];
  __syncthreads();
  const float exv = (c < 100) ? __expf(lg - mx) : 0.f;
  red[c] = exv;
  __syncthreads();
  for (int s = 64; s > 0; s >>= 1) {
    if (c < s) red[c] += red[c + s];
    __syncthreads();
  }
  const float inv = 1.f / red[0];
  if (c < 100) {
    const float val = exv * inv * scale;
    const int ln = ((leaf >> 3) << 5) | (c & 31);
    const int j = leaf & 7;
    const int ct = c >> 5;
    w2pk[(((long)g * 4 + ct) * 64 + ln) * 8 + j] = (f16)val;
  }
}

// ---------------------------------------------------------------------------
// K5: fused query kernel. grid 1024 x 256. Block = 32 queries in LDS (A-frags),
// 4 waves split 38 tree-pairs (exactly 5 groups/wave). Weights stream through a
// per-wave 4x1KB LDS ring via global_load_lds, counted vmcnt (never 0 mid-loop).
// All per-group biases preloaded to registers so the steady-state loop has NO
// stray VMEM ops between the counted waits. LDS total 64.5KB -> 2 blocks/CU.
__global__ __launch_bounds__(256, 2) void k5_query(
    const float* __restrict__ Xq, const float* __restrict__ params,
    const f16* __restrict__ wpk, const f16* __restrict__ w2pk,
    const float* __restrict__ hwit, float* __restrict__ out)
{
  __shared__ __align__(16) unsigned char smem[66048];
  f16* xf    = (f16*)smem;                 // [32 kk][64 lane][8] = 32768 B
  f16* strm  = (f16*)(smem + 32768);       // [4 wave][4 slot][64 lane][8] = 16384 B
  float* du  = (float*)(smem + 49152);     // decs [4][32][33] f32 (16896 B); ored union

  const int tid = threadIdx.x;
  const int lane = tid & 63;
  const int wave = tid >> 6;
  const int qbase = blockIdx.x * 32;
  const float it = hwit[5];
  const int col = lane & 31;
  const int khalf = lane >> 5;

  // ---- stage X (fp32 -> fp16) into exact A-fragment layout
  {
    const int q = tid >> 3;
    const int db = (tid & 7) * 4;
    const float* xr = Xq + (long)(qbase + q) * 512;
    #pragma unroll
    for (int i = 0; i < 16; ++i) {
      const int d = db + i * 32;
      const float4 x4 = *(const float4*)(xr + d);
      const int kk = d >> 4;
      const int ln = q + 32 * ((d & 15) >> 3);
      const int j0 = d & 7;
      f16x4 v;
      v[0] = (f16)x4.x; v[1] = (f16)x4.y; v[2] = (f16)x4.z; v[3] = (f16)x4.w;
      *(f16x4*)(&xf[(kk * 64 + ln) * 8 + j0]) = v;
    }
  }

  // ---- preload all per-group split biases (keeps VMEM out of the main loop)
  auto load_bias = [&](int pp) -> float {
    const int tree = pp * 2 + (col >> 4);
    const int treec = (tree < 75) ? tree : 74;   // pad column: junk, never read
    const int hh2 = treec / 15;
    const int tt2 = treec - hh2 * 15;
    return params[(long)hh2 * TOTAL + I0 + tt2 * 15 + (col & 15)];
  };
  float bnA[5], bnB[5];
  #pragma unroll
  for (int i = 0; i < 5; ++i) {
    const int p = wave + 8 * i;
    bnA[i] = load_bias(p);
    bnB[i] = (p + 4 < NPAIR) ? load_bias(p + 4) : 0.f;
  }
  __syncthreads();

  f32x16 oacc[4];
  #pragma unroll
  for (int ct = 0; ct < 4; ++ct)
    #pragma unroll
    for (int r = 0; r < 16; ++r) oacc[ct][r] = 0.f;

  auto process = [&](const f32x16& S0, const f32x16& S1, int pp, float bn) {
    #pragma unroll
    for (int r = 0; r < 16; ++r) {
      const float z = (S0[r] + S1[r] + bn) * it;
      const float dv = 1.f / (1.f + __expf(-z));
      const int row = (r & 3) + 8 * (r >> 2) + 4 * khalf;
      du[wave * 1056 + row * 33 + col] = dv;
    }
    #pragma unroll
    for (int tf = 0; tf < 2; ++tf) {
      const int g = pp * 2 + tf;
      if (g < 75) {
        const int cb = tf * 16;
        const float* dsr = &du[wave * 1056 + col * 33 + cb];
        const float d0v = dsr[0];
        const float f0 = khalf ? d0v : 1.f - d0v;
        const float d1v = dsr[1 + khalf];
        const float p10 = f0 * (1.f - d1v);
        const float p11 = f0 * d1v;
        const float d2a = dsr[3 + 2 * khalf];
        const float d2b = dsr[4 + 2 * khalf];
        float p2[4];
        p2[0] = p10 * (1.f - d2a);
        p2[1] = p10 * d2a;
        p2[2] = p11 * (1.f - d2b);
        p2[3] = p11 * d2b;
        float d3[4];
        #pragma unroll
        for (int u = 0; u < 4; ++u) d3[u] = dsr[7 + 4 * khalf + u];
        f16x8 rf;
        #pragma unroll
        for (int mm = 0; mm < 8; ++mm) {
          const float rv = p2[mm >> 1] * ((mm & 1) ? d3[mm >> 1] : (1.f - d3[mm >> 1]));
          rf[mm] = (f16)rv;
        }
        const f16x8* w2p = (const f16x8*)w2pk + ((long)g * 4) * 64 + lane;
        oacc[0] = __builtin_amdgcn_mfma_f32_32x32x16_f16(rf, w2p[0],   oacc[0], 0, 0, 0);
        oacc[1] = __builtin_amdgcn_mfma_f32_32x32x16_f16(rf, w2p[64],  oacc[1], 0, 0, 0);
        oacc[2] = __builtin_amdgcn_mfma_f32_32x32x16_f16(rf, w2p[128], oacc[2], 0, 0, 0);
        oacc[3] = __builtin_amdgcn_mfma_f32_32x32x16_f16(rf, w2p[192], oacc[3], 0, 0, 0);
      }
    }
  };

  f16* sb = strm + wave * 2048;  // this wave's 4x512-f16 ring

  // prologue for first group
  const f16* wpa = wpk + (long)wave * 16384;
  const f16* wpb = wpk + (long)(wave + 4) * 16384;
  stage1k(wpa + 0 * 512 + lane * 8, sb + 0 * 512);
  stage1k(wpb + 0 * 512 + lane * 8, sb + 1 * 512);
  stage1k(wpa + 1 * 512 + lane * 8, sb + 2 * 512);
  stage1k(wpb + 1 * 512 + lane * 8, sb + 3 * 512);

  #pragma unroll 1
  for (int i = 0; i < 5; ++i) {
    const int p = wave + 8 * i;
    const bool has2 = (p + 4 < NPAIR);
    f32x16 Sa0, Sa1, Sb0, Sb1;
    #pragma unroll
    for (int r = 0; r < 16; ++r) { Sa0[r] = 0.f; Sa1[r] = 0.f; Sb0[r] = 0.f; Sb1[r] = 0.f; }

    #pragma unroll
    for (int kk = 0; kk < 32; ++kk) {
      // oldest two chunks (this kk's a/b) must have landed; keep 2 in flight
      if (kk < 31) asm volatile("s_waitcnt vmcnt(2)" ::: "memory");
      else         asm volatile("s_waitcnt vmcnt(0)" ::: "memory");
      const int s0 = (2 * kk) & 3;
      const f16x8 af = *(const f16x8*)(&xf[(kk * 64 + lane) * 8]);
      const f16x8 Ba = *(const f16x8*)(&sb[(s0 + 0) * 512 + lane * 8]);
      const f16x8 Bb = *(const f16x8*)(&sb[(s0 + 1) * 512 + lane * 8]);
      if (kk & 1) {
        Sa1 = __builtin_amdgcn_mfma_f32_32x32x16_f16(af, Ba, Sa1, 0, 0, 0);
        Sb1 = __builtin_amdgcn_mfma_f32_32x32x16_f16(af, Bb, Sb1, 0, 0, 0);
      } else {
        Sa0 = __builtin_amdgcn_mfma_f32_32x32x16_f16(af, Ba, Sa0, 0, 0, 0);
        Sb0 = __builtin_amdgcn_mfma_f32_32x32x16_f16(af, Bb, Sb0, 0, 0, 0);
      }
      // ensure slot reads retired before overwriting those slots
      asm volatile("s_waitcnt lgkmcnt(0)" ::: "memory");
      if (kk < 30) {
        stage1k(wpa + (kk + 2) * 512 + lane * 8, sb + (s0 + 0) * 512);
        stage1k(wpb + (kk + 2) * 512 + lane * 8, sb + (s0 + 1) * 512);
      }
    }

    // prologue for next group BEFORE process: its VALU hides the L2 latency
    const f16* wpa2 = wpa;
    const f16* wpb2 = wpb;
    if (i < 4) {
      const int pn = p + 8;
      wpa2 = wpk + (long)pn * 16384;
      wpb2 = wpk + (long)(pn + 4) * 16384;
      stage1k(wpa2 + 0 * 512 + lane * 8, sb + 0 * 512);
      stage1k(wpb2 + 0 * 512 + lane * 8, sb + 1 * 512);
      stage1k(wpa2 + 1 * 512 + lane * 8, sb + 2 * 512);
      stage1k(wpb2 + 1 * 512 + lane * 8, sb + 3 * 512);
    }

    process(Sa0, Sa1, p, bnA[i]);
    if (has2) process(Sb0, Sb1, p + 4, bnB[i]);

    wpa = wpa2; wpb = wpb2;
  }

  // ---- cross-wave reduction of out accumulators + store (du reused as ored)
  __syncthreads();
  #pragma unroll
  for (int ct = 0; ct < 4; ++ct) {
    #pragma unroll
    for (int r = 0; r < 16; ++r) {
      const int row = (r & 3) + 8 * (r >> 2) + 4 * khalf;
      du[wave * 1024 + row * 32 + col] = oacc[ct][r];
    }
    __syncthreads();
    for (int e = tid; e < 1024; e += 256) {
      const float sm = du[e] + du[1024 + e] + du[2048 + e] + du[3072 + e];
      const int q = e >> 5;
      const int c = ct * 32 + (e & 31);
      if (c < 100) out[(long)(qbase + q) * 100 + c] = sm;
    }
    __syncthreads();
  }
}

// ---------------------------------------------------------------------------
extern "C" void kernel_launch(void* const* d_in, const int* in_sizes, int n_in,
                              void* d_out, int out_size, void* d_ws, size_t ws_size,
                              hipStream_t stream) {
  (void)in_sizes; (void)n_in; (void)out_size; (void)ws_size;
  const float* Xs  = (const float*)d_in[0];
  const float* Xq  = (const float*)d_in[1];
  const float* ew1 = (const float*)d_in[2];
  const float* eb1 = (const float*)d_in[3];
  const float* lng = (const float*)d_in[4];
  const float* lnb = (const float*)d_in[5];
  const float* ew2 = (const float*)d_in[6];
  const float* eb2 = (const float*)d_in[7];
  const float* gw1 = (const float*)d_in[8];
  const float* gb1 = (const float*)d_in[9];
  const float* gw2 = (const float*)d_in[10];
  const float* gb2 = (const float*)d_in[11];
  const float* hwi = (const float*)d_in[12];
  const float* tmp = (const float*)d_in[13];
  float* out = (float*)d_out;

  // ws layout (bytes), all 64B-aligned; wpk gets one extra zero pair (pad for wave 3's
  // wpb prologue pointer p+4=39... p max = 35, p+4 = 39? no: preload guards; but the
  // FIRST prologue loads pair wave+4 <= 7 < 38 always, and mid-loop pn+4 <= 35+? see k5)
  char* ws = (char*)d_ws;
  float* params = (float*)(ws);                              // 2,788,800
  f16*   wpk    = (f16*)(ws + 2788800);                      // 1,245,184
  f16*   w2pk   = (f16*)(ws + 2788800 + 1245184);            //   307,200
  float* ctxs   = (float*)(ws + 4341184);                    //     1,280
  float* gbuf   = (float*)(ws + 4342464);                    //     2,560
  float* hwit   = (float*)(ws + 4345024);                    //        32

  hipMemsetAsync(ctxs, 0, 1280, stream);
  hipMemsetAsync(w2pk, 0, 307200, stream);

  k1_encode<<<dim3(128, 5), 256, 0, stream>>>(Xs, ew1, eb1, lng, lnb, ew2, ctxs);
  k2_ctx<<<1, 256, 0, stream>>>(eb2, gw1, gb1, hwi, tmp, ctxs, gbuf, hwit);
  k3_params<<<dim3(137, 5), 256, 0, stream>>>(gbuf, gw2, gb2, params);
  k4a_packw<<<304, 256, 0, stream>>>(params, wpk);
  k4b_w2<<<1200, 128, 0, stream>>>(params, hwit, w2pk);
  k5_query<<<1024, 256, 0, stream>>>(Xq, params, wpk, w2pk, hwit, out);
}